// Round 1
// baseline (267.860 us; speedup 1.0000x reference)
//
#include <hip/hip_runtime.h>
#include <hip/hip_bf16.h>

#define HEADS 8
#define HEADC 16
#define CCH   128
#define C3    384
#define NPIX  16384
#define BATCH 8
#define LN_EPS 1e-5f

typedef __bf16 bf16x8 __attribute__((ext_vector_type(8)));
typedef float  f32x4  __attribute__((ext_vector_type(4)));
typedef unsigned short u16;

__device__ __forceinline__ u16 f2bf(float f) {
    __bf16 b = (__bf16)f;
    return __builtin_bit_cast(u16, b);
}
__device__ __forceinline__ float bf2f(u16 u) {
    return (float)__builtin_bit_cast(__bf16, u);
}
__device__ __forceinline__ bf16x8 zero8() {
    bf16x8 v;
#pragma unroll
    for (int j = 0; j < 8; j++) v[j] = (__bf16)0.f;
    return v;
}

// ---------------------------------------------------------------------------
// prep: pack weights into bf16 MFMA B-fragment order.
// For tile t (out0=t*16), kstep s (k0=s*32), lane l, elem j:
//   dst[((t*4+s)*64+l)*8+j] = bf16(src[(t*16+(l&15))*128 + s*32 + ((l>>4)&3)*8 + j])
// Covers qkv_w (24 tiles), o1_w (8), o2_w (8).  81920 elements total.
// ---------------------------------------------------------------------------
__global__ __launch_bounds__(256) void prep_kernel(
    const float* __restrict__ qkv_w, const float* __restrict__ o1_w,
    const float* __restrict__ o2_w, u16* __restrict__ wq,
    u16* __restrict__ o1f, u16* __restrict__ o2f) {
    int i = blockIdx.x * 256 + threadIdx.x;
    if (i >= 81920) return;
    int j = i;
    const float* src;
    u16* dst;
    if (j < 49152) { src = qkv_w; dst = wq; }
    else if (j < 65536) { j -= 49152; src = o1_w; dst = o1f; }
    else { j -= 65536; src = o2_w; dst = o2f; }
    int jj = j & 7;
    int l  = (j >> 3) & 63;
    int s  = (j >> 9) & 3;
    int t  = j >> 11;
    int outc = t * 16 + (l & 15);
    int k    = s * 32 + ((l >> 4) & 3) * 8 + jj;
    dst[j] = f2bf(src[outc * 128 + k]);
}

// ---------------------------------------------------------------------------
// k1: qkv GEMM + LN(k),LN(v) + per-block k^T v partials + store q (bf16)
// grid 2048 = B * (N/64); block 256 (4 waves); 64-row tiles
// ---------------------------------------------------------------------------
__global__ __launch_bounds__(256, 2) void k1(
    const float* __restrict__ x, const u16* __restrict__ wq,
    const float* __restrict__ qkv_b,
    const float* __restrict__ klw, const float* __restrict__ klb,
    const float* __restrict__ vlw, const float* __restrict__ vlb,
    u16* __restrict__ q_ws, float* __restrict__ part) {
    __shared__ u16 x_a[64 * 136];          // [n][c] bf16, A-operand layout
    __shared__ u16 qkv_s[64 * 392 + 16];   // [n][384] bf16

    const int tid  = threadIdx.x;
    const int lane = tid & 63;
    const int wv   = tid >> 6;
    const int bid  = blockIdx.x;
    const int b    = bid >> 8;
    const int n0   = (bid & 255) * 64;

    // phase 1: load x tile [128 c][64 n], transpose to x_a[n][c] bf16
    {
        int c = tid >> 1, half = tid & 1;
        const float4* s4 = (const float4*)(x + ((size_t)(b * CCH + c)) * NPIX + n0 + half * 32);
#pragma unroll
        for (int i = 0; i < 8; i++) {
            float4 v = s4[i];
            int n = half * 32 + i * 4;
            x_a[(n + 0) * 136 + c] = f2bf(v.x);
            x_a[(n + 1) * 136 + c] = f2bf(v.y);
            x_a[(n + 2) * 136 + c] = f2bf(v.z);
            x_a[(n + 3) * 136 + c] = f2bf(v.w);
        }
    }
    __syncthreads();

    // phase 2: qkv[64,384] = x[64,128] @ W^T ; wave wv owns rows [wv*16, wv*16+16)
    const int m16  = wv * 16;
    const int l15  = lane & 15;
    const int quad = lane >> 4;
    f32x4 acc[24];
#pragma unroll
    for (int t = 0; t < 24; t++) acc[t] = (f32x4){0.f, 0.f, 0.f, 0.f};
    bf16x8 af[4];
#pragma unroll
    for (int s = 0; s < 4; s++)
        af[s] = *(const bf16x8*)&x_a[(m16 + l15) * 136 + s * 32 + quad * 8];
#pragma unroll
    for (int t = 0; t < 24; t++) {
#pragma unroll
        for (int s = 0; s < 4; s++) {
            bf16x8 bf = *(const bf16x8*)(wq + (size_t)((t * 4 + s) * 64 + lane) * 8);
            acc[t] = __builtin_amdgcn_mfma_f32_16x16x32_bf16(af[s], bf, acc[t], 0, 0, 0);
        }
    }

    // phase 3: write qkv (+bias) to LDS.  D layout: col=lane&15, row=quad*4+r
#pragma unroll
    for (int t = 0; t < 24; t++) {
        int col = t * 16 + l15;
        float bv = qkv_b[col];
#pragma unroll
        for (int r = 0; r < 4; r++)
            qkv_s[(m16 + quad * 4 + r) * 392 + col] = f2bf(acc[t][r] + bv);
    }
    __syncthreads();

    // phase 4: LayerNorm of k and v rows (d=16, ddof=1, eps added to std)
#pragma unroll
    for (int it = 0; it < 4; it++) {
        int task  = tid + it * 256;           // 1024 tasks: 64 rows x 8 heads x {k,v}
        int row   = task & 63;
        int h     = (task >> 6) & 7;
        int which = (task >> 9) & 1;          // 0=k, 1=v
        u16* p = &qkv_s[row * 392 + h * 48 + 16 + which * 16];
        bf16x8 v0 = *(const bf16x8*)p;
        bf16x8 v1 = *(const bf16x8*)(p + 8);
        float vals[16];
#pragma unroll
        for (int d = 0; d < 8; d++) { vals[d] = (float)v0[d]; vals[8 + d] = (float)v1[d]; }
        float s = 0.f, sq = 0.f;
#pragma unroll
        for (int d = 0; d < 16; d++) { s += vals[d]; sq += vals[d] * vals[d]; }
        float mean = s * (1.f / 16.f);
        float var  = (sq - 16.f * mean * mean) * (1.f / 15.f);
        var = var < 0.f ? 0.f : var;
        float inv = 1.f / (sqrtf(var) + LN_EPS);
        const float* lw = (which ? vlw : klw) + h * 16;
        const float* lb = (which ? vlb : klb) + h * 16;
        bf16x8 o0, o1;
#pragma unroll
        for (int d = 0; d < 8; d++) {
            o0[d] = (__bf16)((vals[d] - mean) * inv * lw[d] + lb[d]);
            o1[d] = (__bf16)((vals[8 + d] - mean) * inv * lw[8 + d] + lb[8 + d]);
        }
        *(bf16x8*)p = o0;
        *(bf16x8*)(p + 8) = o1;
    }
    __syncthreads();

    // phase 5: store q (bf16) to workspace, channel layout c = h*16 + d
#pragma unroll
    for (int it = 0; it < 2; it++) {
        int task = tid + it * 256;            // 512 tasks: 64 rows x 8 heads
        int row  = task >> 3;
        int h    = task & 7;
        const uint4* src = (const uint4*)&qkv_s[row * 392 + h * 48];
        uint4* dst = (uint4*)(q_ws + ((size_t)(b * NPIX) + n0 + row) * 128 + h * 16);
        dst[0] = src[0];
        dst[1] = src[1];
    }

    // phase 6: per-block k^T v partials (one (h,dk,dv-chunk) per thread)
    {
        int h   = tid >> 5;
        int dk  = (tid >> 1) & 15;
        int dvh = tid & 1;
        float a8[8];
#pragma unroll
        for (int j = 0; j < 8; j++) a8[j] = 0.f;
        for (int row = 0; row < 64; row++) {
            float kval = bf2f(qkv_s[row * 392 + h * 48 + 16 + dk]);
            bf16x8 vv = *(const bf16x8*)&qkv_s[row * 392 + h * 48 + 32 + dvh * 8];
#pragma unroll
            for (int j = 0; j < 8; j++) a8[j] += kval * (float)vv[j];
        }
        float* pd = part + (size_t)bid * 2048 + h * 256 + dk * 16 + dvh * 8;
        *(float4*)pd       = (float4){a8[0], a8[1], a8[2], a8[3]};
        *(float4*)(pd + 4) = (float4){a8[4], a8[5], a8[6], a8[7]};
    }
}

// ---------------------------------------------------------------------------
// k_red: kv[b][e] = (1/N) * sum over 256 tiles of partials
// ---------------------------------------------------------------------------
__global__ __launch_bounds__(256) void k_red(const float* __restrict__ part,
                                             float* __restrict__ kv_g) {
    int gid = blockIdx.x * 256 + threadIdx.x;   // 16384
    int b = gid >> 11, e = gid & 2047;
    float s = 0.f;
    for (int t = 0; t < 256; t++) s += part[((size_t)(b * 256 + t)) * 2048 + e];
    kv_g[gid] = s * (1.f / 16384.f);
}

// ---------------------------------------------------------------------------
// k2: av = q@kv, ret = av + x, h1 = gelu(ret@o1^T+b1), out = h1@o2^T + b2 + x
// grid 2048; block 256; 64-row tiles
// ---------------------------------------------------------------------------
__global__ __launch_bounds__(256, 2) void k2(
    const float* __restrict__ x, const u16* __restrict__ q_ws,
    const float* __restrict__ kv_g, const u16* __restrict__ o1f,
    const u16* __restrict__ o2f, const float* __restrict__ o1_b,
    const float* __restrict__ o2_b, float* __restrict__ out) {
    __shared__ u16 a_s[64 * 136 + 32];   // q -> ret -> h1 (bf16, A-operand layout)
    __shared__ float x_s[128 * 68];      // x tile [c][n], later out tile
    __shared__ float kv_s[2048];         // [h][dk][dv]

    const int tid  = threadIdx.x;
    const int lane = tid & 63;
    const int wv   = tid >> 6;
    const int bid  = blockIdx.x;
    const int b    = bid >> 8;
    const int n0   = (bid & 255) * 64;

    // phase 1: stage q, x, kv
    {
        int row = tid >> 2, seg = tid & 3;
        const uint4* qs = (const uint4*)(q_ws + ((size_t)(b * NPIX) + n0 + row) * 128 + seg * 32);
        uint4* qd = (uint4*)&a_s[row * 136 + seg * 32];
#pragma unroll
        for (int i = 0; i < 4; i++) qd[i] = qs[i];

        int c = tid >> 1, half = tid & 1;
        const float4* xs = (const float4*)(x + ((size_t)(b * CCH + c)) * NPIX + n0 + half * 32);
        float4* xd = (float4*)&x_s[c * 68 + half * 32];
#pragma unroll
        for (int i = 0; i < 8; i++) xd[i] = xs[i];

        const float4* ks = (const float4*)(kv_g + b * 2048 + tid * 8);
        float4* kd = (float4*)&kv_s[tid * 8];
        kd[0] = ks[0];
        kd[1] = ks[1];
    }
    __syncthreads();

    const int m16  = wv * 16;
    const int l15  = lane & 15;
    const int quad = lane >> 4;

    // phase 2: av per head via MFMA (K=32, upper 16 zero in BOTH A and B), ret = av + x
    float retv[8][4];
#pragma unroll
    for (int h = 0; h < 8; h++) {
        bf16x8 afr, bfr;
        if (quad < 2) {
#pragma unroll
            for (int j = 0; j < 8; j++)
                bfr[j] = (__bf16)kv_s[h * 256 + (quad * 8 + j) * 16 + l15];
            afr = *(const bf16x8*)&a_s[(m16 + l15) * 136 + h * 16 + quad * 8];
        } else {
            afr = zero8();
            bfr = zero8();
        }
        f32x4 acc = (f32x4){0.f, 0.f, 0.f, 0.f};
        acc = __builtin_amdgcn_mfma_f32_16x16x32_bf16(afr, bfr, acc, 0, 0, 0);
#pragma unroll
        for (int r = 0; r < 4; r++) {
            int row = m16 + quad * 4 + r;
            int col = h * 16 + l15;
            retv[h][r] = acc[r] + x_s[col * 68 + row];
        }
    }
    __builtin_amdgcn_wave_barrier();   // all q reads before ret overwrites a_s
#pragma unroll
    for (int h = 0; h < 8; h++)
#pragma unroll
        for (int r = 0; r < 4; r++)
            a_s[(m16 + quad * 4 + r) * 136 + h * 16 + l15] = f2bf(retv[h][r]);
    __builtin_amdgcn_wave_barrier();

    // phase 3: h1 = gelu(ret @ o1^T + b1)   (rows are wave-private; no block sync)
    f32x4 acc2[8];
    bf16x8 af2[4];
#pragma unroll
    for (int t = 0; t < 8; t++) acc2[t] = (f32x4){0.f, 0.f, 0.f, 0.f};
#pragma unroll
    for (int s = 0; s < 4; s++)
        af2[s] = *(const bf16x8*)&a_s[(m16 + l15) * 136 + s * 32 + quad * 8];
#pragma unroll
    for (int t = 0; t < 8; t++)
#pragma unroll
        for (int s = 0; s < 4; s++) {
            bf16x8 bf = *(const bf16x8*)(o1f + (size_t)((t * 4 + s) * 64 + lane) * 8);
            acc2[t] = __builtin_amdgcn_mfma_f32_16x16x32_bf16(af2[s], bf, acc2[t], 0, 0, 0);
        }
    float g[8][4];
#pragma unroll
    for (int t = 0; t < 8; t++) {
        float bb = o1_b[t * 16 + l15];
#pragma unroll
        for (int r = 0; r < 4; r++) {
            float v = acc2[t][r] + bb;
            g[t][r] = 0.5f * v * (1.f + erff(v * 0.70710678118654752f));
        }
    }
    __builtin_amdgcn_wave_barrier();
#pragma unroll
    for (int t = 0; t < 8; t++)
#pragma unroll
        for (int r = 0; r < 4; r++)
            a_s[(m16 + quad * 4 + r) * 136 + t * 16 + l15] = f2bf(g[t][r]);
    __builtin_amdgcn_wave_barrier();

    // phase 4: out = h1 @ o2^T + b2 + x   (into x_s in place)
#pragma unroll
    for (int t = 0; t < 8; t++) acc2[t] = (f32x4){0.f, 0.f, 0.f, 0.f};
#pragma unroll
    for (int s = 0; s < 4; s++)
        af2[s] = *(const bf16x8*)&a_s[(m16 + l15) * 136 + s * 32 + quad * 8];
#pragma unroll
    for (int t = 0; t < 8; t++)
#pragma unroll
        for (int s = 0; s < 4; s++) {
            bf16x8 bf = *(const bf16x8*)(o2f + (size_t)((t * 4 + s) * 64 + lane) * 8);
            acc2[t] = __builtin_amdgcn_mfma_f32_16x16x32_bf16(af2[s], bf, acc2[t], 0, 0, 0);
        }
#pragma unroll
    for (int t = 0; t < 8; t++) {
        float bb = o2_b[t * 16 + l15];
#pragma unroll
        for (int r = 0; r < 4; r++) {
            int row = m16 + quad * 4 + r;
            int col = t * 16 + l15;
            x_s[col * 68 + row] = acc2[t][r] + bb + x_s[col * 68 + row];
        }
    }
    __syncthreads();

    // phase 5: coalesced fp32 store, [c][n] layout
    {
        int c = tid >> 1, half = tid & 1;
        float4* dst = (float4*)(out + ((size_t)(b * CCH + c)) * NPIX + n0 + half * 32);
        const float4* sv = (const float4*)&x_s[c * 68 + half * 32];
#pragma unroll
        for (int i = 0; i < 8; i++) dst[i] = sv[i];
    }
}

// ---------------------------------------------------------------------------
extern "C" void kernel_launch(void* const* d_in, const int* in_sizes, int n_in,
                              void* d_out, int out_size, void* d_ws, size_t ws_size,
                              hipStream_t stream) {
    (void)in_sizes; (void)n_in; (void)out_size; (void)ws_size;
    const float* x     = (const float*)d_in[0];
    const float* qkv_w = (const float*)d_in[1];
    const float* qkv_b = (const float*)d_in[2];
    const float* o1_w  = (const float*)d_in[3];
    const float* o1_b  = (const float*)d_in[4];
    const float* o2_w  = (const float*)d_in[5];
    const float* o2_b  = (const float*)d_in[6];
    const float* klw   = (const float*)d_in[7];
    const float* klb   = (const float*)d_in[8];
    const float* vlw   = (const float*)d_in[9];
    const float* vlb   = (const float*)d_in[10];
    float* outp = (float*)d_out;

    char* ws = (char*)d_ws;
    float* kv_g = (float*)(ws);                  // 16384 f  (64 KB)
    u16*   wq   = (u16*)(ws + 65536);            // 49152 bf16 (96 KB)
    u16*   o1f  = (u16*)(ws + 163840);           // 16384 bf16 (32 KB)
    u16*   o2f  = (u16*)(ws + 196608);           // 16384 bf16 (32 KB)
    float* part = (float*)(ws + 229376);         // 2048*2048 f (16 MB)
    u16*   q_ws = (u16*)(ws + 17006592);         // 8*16384*128 bf16 (32 MB)

    prep_kernel<<<320, 256, 0, stream>>>(qkv_w, o1_w, o2_w, wq, o1f, o2f);
    k1<<<2048, 256, 0, stream>>>(x, wq, qkv_b, klw, klb, vlw, vlb, q_ws, part);
    k_red<<<64, 256, 0, stream>>>(part, kv_g);
    k2<<<2048, 256, 0, stream>>>(x, q_ws, kv_g, o1f, o2f, o1_b, o2_b, outp);
}

// Round 2
// 250.884 us; speedup vs baseline: 1.0677x; 1.0677x over previous
//
#include <hip/hip_runtime.h>
#include <hip/hip_bf16.h>

#define LN_EPS 1e-5f

typedef __bf16 bf16x8 __attribute__((ext_vector_type(8)));
typedef float  f32x4  __attribute__((ext_vector_type(4)));
typedef unsigned int u32x4 __attribute__((ext_vector_type(4)));
typedef unsigned short u16;
typedef unsigned int u32;

__device__ __forceinline__ u16 f2bf(float f) {
    __bf16 b = (__bf16)f;
    return __builtin_bit_cast(u16, b);
}
__device__ __forceinline__ bf16x8 zero8() {
    bf16x8 v;
#pragma unroll
    for (int j = 0; j < 8; j++) v[j] = (__bf16)0.f;
    return v;
}

// ---------------------------------------------------------------------------
// prep: pack weights into bf16 MFMA B-fragment order (16x16x32).
// dst[((t*4+s)*64+l)*8+j] = bf16(src[(t*16+(l&15))*128 + s*32 + ((l>>4)&3)*8 + j])
// ---------------------------------------------------------------------------
__global__ __launch_bounds__(256) void prep_kernel(
    const float* __restrict__ qkv_w, const float* __restrict__ o1_w,
    const float* __restrict__ o2_w, u16* __restrict__ wq,
    u16* __restrict__ o1f, u16* __restrict__ o2f) {
    int i = blockIdx.x * 256 + threadIdx.x;
    if (i >= 81920) return;
    int j = i;
    const float* src;
    u16* dst;
    if (j < 49152) { src = qkv_w; dst = wq; }
    else if (j < 65536) { j -= 49152; src = o1_w; dst = o1f; }
    else { j -= 65536; src = o2_w; dst = o2f; }
    int jj = j & 7;
    int l  = (j >> 3) & 63;
    int s  = (j >> 9) & 3;
    int t  = j >> 11;
    int outc = t * 16 + (l & 15);
    int k    = s * 32 + ((l >> 4) & 3) * 8 + jj;
    dst[j] = f2bf(src[outc * 128 + k]);
}

// ---------------------------------------------------------------------------
// k1: qkv GEMM + in-register LN(k,v) + per-block k^T v partial via MFMA + q out
// grid 2048 = B * (N/64); block 512 (8 waves: 4 row-stripes x 2 head-halves)
// ---------------------------------------------------------------------------
__global__ __launch_bounds__(512, 5) void k1(
    const float* __restrict__ x, const u16* __restrict__ wq,
    const float* __restrict__ qkv_b,
    const float* __restrict__ klw, const float* __restrict__ klb,
    const float* __restrict__ vlw, const float* __restrict__ vlb,
    u16* __restrict__ q_ws, float* __restrict__ part) {
    __shared__ u16 smem[2 * 64 * 136];          // x_a | q_s ; kvred overlays later
    u16* x_a = smem;
    u16* q_s = smem + 64 * 136;
    float* kvred = (float*)smem;                 // 8 h x 4 stripes x 64 lanes x 4 = 32KB

    const int tid  = threadIdx.x;
    const int lane = tid & 63;
    const int wv   = tid >> 6;
    const int stripe = wv >> 1;
    const int half   = wv & 1;
    const int bid  = blockIdx.x;
    const int b    = bid >> 8;
    const int n0   = (bid & 255) * 64;

    // stage x tile [128 c][64 n] -> bf16 A-layout x_a[n][c]
    {
        int c = tid >> 2, nq = (tid & 3) * 16;
        const float4* s4 = (const float4*)(x + ((size_t)(b * 128 + c)) * 16384 + n0 + nq);
#pragma unroll
        for (int i = 0; i < 4; i++) {
            float4 v = s4[i];
            int n = nq + i * 4;
            x_a[(n + 0) * 136 + c] = f2bf(v.x);
            x_a[(n + 1) * 136 + c] = f2bf(v.y);
            x_a[(n + 2) * 136 + c] = f2bf(v.z);
            x_a[(n + 3) * 136 + c] = f2bf(v.w);
        }
    }
    __syncthreads();

    const int m16  = stripe * 16;
    const int l15  = lane & 15;
    const int quad = lane >> 4;
    const bool act = quad < 2;
    // shuffle sources for D-layout -> A/B-fragment quad permute
    const int sA = (((quad << 1) * 16) + l15) & 63;
    const int sB = (sA + 16) & 63;

    bf16x8 af[4];
#pragma unroll
    for (int s = 0; s < 4; s++)
        af[s] = *(const bf16x8*)&x_a[(m16 + l15) * 136 + s * 32 + quad * 8];

    const int tb = half * 12;
    const int h0 = half * 4;
    f32x4 kvacc[4];

#pragma unroll
    for (int hh = 0; hh < 4; hh++) {
        const int tq = tb + 3 * hh;
        f32x4 aq = (f32x4){0.f,0.f,0.f,0.f};
        f32x4 ak = (f32x4){0.f,0.f,0.f,0.f};
        f32x4 avv = (f32x4){0.f,0.f,0.f,0.f};
#pragma unroll
        for (int s = 0; s < 4; s++) {
            bf16x8 bq = *(const bf16x8*)(wq + (size_t)(((tq + 0) * 4 + s) * 64 + lane) * 8);
            bf16x8 bk = *(const bf16x8*)(wq + (size_t)(((tq + 1) * 4 + s) * 64 + lane) * 8);
            bf16x8 bv = *(const bf16x8*)(wq + (size_t)(((tq + 2) * 4 + s) * 64 + lane) * 8);
            aq  = __builtin_amdgcn_mfma_f32_16x16x32_bf16(af[s], bq, aq, 0, 0, 0);
            ak  = __builtin_amdgcn_mfma_f32_16x16x32_bf16(af[s], bk, ak, 0, 0, 0);
            avv = __builtin_amdgcn_mfma_f32_16x16x32_bf16(af[s], bv, avv, 0, 0, 0);
        }
        const int h = h0 + hh;
        float biasq = qkv_b[(tq + 0) * 16 + l15];
        float biask = qkv_b[(tq + 1) * 16 + l15];
        float biasv = qkv_b[(tq + 2) * 16 + l15];

        // q (+bias) -> q_s in A-layout
#pragma unroll
        for (int r = 0; r < 4; r++)
            q_s[(m16 + quad * 4 + r) * 136 + h * 16 + l15] = f2bf(aq[r] + biasq);

        // in-register LayerNorm over d=16 (the 16 l15 lanes), per row r
        float kb4[4], vb4[4], ks[4], ksq[4], vs[4], vsq[4];
#pragma unroll
        for (int r = 0; r < 4; r++) {
            kb4[r] = ak[r] + biask;  vb4[r] = avv[r] + biasv;
            ks[r] = kb4[r]; ksq[r] = kb4[r] * kb4[r];
            vs[r] = vb4[r]; vsq[r] = vb4[r] * vb4[r];
        }
#pragma unroll
        for (int m = 1; m < 16; m <<= 1) {
#pragma unroll
            for (int r = 0; r < 4; r++) {
                ks[r]  += __shfl_xor(ks[r], m);
                ksq[r] += __shfl_xor(ksq[r], m);
                vs[r]  += __shfl_xor(vs[r], m);
                vsq[r] += __shfl_xor(vsq[r], m);
            }
        }
        float kw = klw[h * 16 + l15], kbb = klb[h * 16 + l15];
        float vw = vlw[h * 16 + l15], vbb = vlb[h * 16 + l15];
        u16 kn[4], vn[4];
#pragma unroll
        for (int r = 0; r < 4; r++) {
            float km = ks[r] * (1.f / 16.f);
            float kvar = (ksq[r] - 16.f * km * km) * (1.f / 15.f);
            kvar = kvar < 0.f ? 0.f : kvar;
            float kinv = 1.f / (sqrtf(kvar) + LN_EPS);
            kn[r] = f2bf((kb4[r] - km) * kinv * kw + kbb);
            float vm = vs[r] * (1.f / 16.f);
            float vvar = (vsq[r] - 16.f * vm * vm) * (1.f / 15.f);
            vvar = vvar < 0.f ? 0.f : vvar;
            float vinv = 1.f / (sqrtf(vvar) + LN_EPS);
            vn[r] = f2bf((vb4[r] - vm) * vinv * vw + vbb);
        }
        // pack D-layout regs, quad-permute into A/B fragments, one MFMA = k^T v
        u32 kp0 = (u32)kn[0] | ((u32)kn[1] << 16);
        u32 kp1 = (u32)kn[2] | ((u32)kn[3] << 16);
        u32 vp0 = (u32)vn[0] | ((u32)vn[1] << 16);
        u32 vp1 = (u32)vn[2] | ((u32)vn[3] << 16);
        u32 f0 = (u32)__shfl((int)kp0, sA); u32 f1 = (u32)__shfl((int)kp1, sA);
        u32 f2 = (u32)__shfl((int)kp0, sB); u32 f3 = (u32)__shfl((int)kp1, sB);
        u32 g0 = (u32)__shfl((int)vp0, sA); u32 g1 = (u32)__shfl((int)vp1, sA);
        u32 g2 = (u32)__shfl((int)vp0, sB); u32 g3 = (u32)__shfl((int)vp1, sB);
        if (!act) { f0 = f1 = f2 = f3 = 0u; g0 = g1 = g2 = g3 = 0u; }
        bf16x8 Af = __builtin_bit_cast(bf16x8, (u32x4){f0, f1, f2, f3});
        bf16x8 Bf = __builtin_bit_cast(bf16x8, (u32x4){g0, g1, g2, g3});
        kvacc[hh] = __builtin_amdgcn_mfma_f32_16x16x32_bf16(
            Af, Bf, (f32x4){0.f,0.f,0.f,0.f}, 0, 0, 0);
    }
    __syncthreads();   // q_s complete; x_a reads done

    // drain q (bf16) to workspace, coalesced
    {
        int row = tid >> 3, seg = tid & 7;
        const uint4* sq = (const uint4*)&q_s[row * 136 + seg * 16];
        uint4* dq = (uint4*)(q_ws + ((size_t)(b * 16384) + n0 + row) * 128 + seg * 16);
        dq[0] = sq[0];
        dq[1] = sq[1];
    }
    __syncthreads();   // smem free -> kvred overlay

    // stage per-wave kv partials, reduce over 4 stripes -> part
#pragma unroll
    for (int hh = 0; hh < 4; hh++) {
        int h = h0 + hh;
        float* p = &kvred[(((h * 4 + stripe) * 64) + lane) * 4];
        *(float4*)p = (float4){kvacc[hh][0], kvacc[hh][1], kvacc[hh][2], kvacc[hh][3]};
    }
    __syncthreads();
#pragma unroll
    for (int it = 0; it < 4; it++) {
        int e = tid + it * 512;
        int h = e >> 8, dk = (e >> 4) & 15, dv = e & 15;
        int ls = ((dk >> 2) << 4) | dv;
        int r  = dk & 3;
        float s = 0.f;
#pragma unroll
        for (int st = 0; st < 4; st++)
            s += kvred[((h * 4 + st) * 64 + ls) * 4 + r];
        part[(size_t)bid * 2048 + e] = s;
    }
}

// ---------------------------------------------------------------------------
// k_red: kv = (1/N) * sum of partials; emit bf16 B-fragment layout for k2
// kvf[(b*8+h)*256 + (dk>>3)*128 + dv*8 + (dk&7)]
// ---------------------------------------------------------------------------
__global__ __launch_bounds__(256) void k_red(const float* __restrict__ part,
                                             u16* __restrict__ kvf) {
    int gid = blockIdx.x * 256 + threadIdx.x;   // 16384
    int b = gid >> 11, e = gid & 2047;
    float s = 0.f;
    for (int t = 0; t < 256; t++) s += part[((size_t)(b * 256 + t)) * 2048 + e];
    float val = s * (1.f / 16384.f);
    int h = e >> 8, dk = (e >> 4) & 15, dv = e & 15;
    kvf[(size_t)(b * 8 + h) * 256 + (dk >> 3) * 128 + dv * 8 + (dk & 7)] = f2bf(val);
}

// ---------------------------------------------------------------------------
// k2: av = q@kv, ret = av+x, h1 = gelu(ret@o1^T+b1), out = h1@o2^T+b2+x
// grid 4096 = B * (N/32); block 256 (4 waves: 2 row-stripes x 2 tile-halves)
// ---------------------------------------------------------------------------
__global__ __launch_bounds__(256, 5) void k2(
    const float* __restrict__ x, const u16* __restrict__ q_ws,
    const u16* __restrict__ kvf, const u16* __restrict__ o1f,
    const u16* __restrict__ o2f, const float* __restrict__ o1_b,
    const float* __restrict__ o2_b, float* __restrict__ out) {
    __shared__ u16 a_s[32 * 136];      // q -> ret -> h1 (A-layout)
    __shared__ float x_s[128 * 36];    // x [c][n]; becomes out in place

    const int tid  = threadIdx.x;
    const int lane = tid & 63;
    const int wv   = tid >> 6;
    const int stripe = wv >> 1;
    const int half   = wv & 1;
    const int bid  = blockIdx.x;
    const int b    = bid >> 9;
    const int n0   = (bid & 511) * 32;

    // stage q and x
    {
        int row = tid >> 3, seg = tid & 7;
        const uint4* qs = (const uint4*)(q_ws + ((size_t)(b * 16384) + n0 + row) * 128 + seg * 16);
        uint4* qd = (uint4*)&a_s[row * 136 + seg * 16];
        qd[0] = qs[0];
        qd[1] = qs[1];

        int c = tid >> 1, nh = (tid & 1) * 16;
        const float4* xs = (const float4*)(x + ((size_t)(b * 128 + c)) * 16384 + n0 + nh);
        float4* xd = (float4*)&x_s[c * 36 + nh];
#pragma unroll
        for (int i = 0; i < 4; i++) xd[i] = xs[i];
    }
    __syncthreads();

    const int m16  = stripe * 16;
    const int l15  = lane & 15;
    const int quad = lane >> 4;
    const bool act = quad < 2;

    // av per head (4 heads per wave), ret = av + x
    float retv[4][4];
#pragma unroll
    for (int hh = 0; hh < 4; hh++) {
        int h = half * 4 + hh;
        bf16x8 afr = zero8(), bfr = zero8();
        if (act) {
            afr = *(const bf16x8*)&a_s[(m16 + l15) * 136 + h * 16 + quad * 8];
            bfr = *(const bf16x8*)(kvf + (size_t)(b * 8 + h) * 256 + quad * 128 + l15 * 8);
        }
        f32x4 acc = __builtin_amdgcn_mfma_f32_16x16x32_bf16(
            afr, bfr, (f32x4){0.f,0.f,0.f,0.f}, 0, 0, 0);
#pragma unroll
        for (int r = 0; r < 4; r++)
            retv[hh][r] = acc[r] + x_s[(h * 16 + l15) * 36 + m16 + quad * 4 + r];
    }
    // write ret into wave-private region of a_s
#pragma unroll
    for (int hh = 0; hh < 4; hh++)
#pragma unroll
        for (int r = 0; r < 4; r++)
            a_s[(m16 + quad * 4 + r) * 136 + (half * 4 + hh) * 16 + l15] = f2bf(retv[hh][r]);
    __syncthreads();

    // o1: 4 t-tiles per wave over full-128 rows
    bf16x8 af2[4];
#pragma unroll
    for (int s = 0; s < 4; s++)
        af2[s] = *(const bf16x8*)&a_s[(m16 + l15) * 136 + s * 32 + quad * 8];
    f32x4 acc2[4];
#pragma unroll
    for (int t = 0; t < 4; t++) acc2[t] = (f32x4){0.f,0.f,0.f,0.f};
#pragma unroll
    for (int tt = 0; tt < 4; tt++) {
        int t = half * 4 + tt;
#pragma unroll
        for (int s = 0; s < 4; s++) {
            bf16x8 bf = *(const bf16x8*)(o1f + (size_t)((t * 4 + s) * 64 + lane) * 8);
            acc2[tt] = __builtin_amdgcn_mfma_f32_16x16x32_bf16(af2[s], bf, acc2[tt], 0, 0, 0);
        }
    }
    float g[4][4];
#pragma unroll
    for (int tt = 0; tt < 4; tt++) {
        float bb = o1_b[(half * 4 + tt) * 16 + l15];
#pragma unroll
        for (int r = 0; r < 4; r++) {
            float v = acc2[tt][r] + bb;
            g[tt][r] = 0.5f * v * (1.f + erff(v * 0.70710678118654752f));
        }
    }
    __syncthreads();    // all ret-fragment reads done
#pragma unroll
    for (int tt = 0; tt < 4; tt++)
#pragma unroll
        for (int r = 0; r < 4; r++)
            a_s[(m16 + quad * 4 + r) * 136 + (half * 4 + tt) * 16 + l15] = f2bf(g[tt][r]);
    __syncthreads();

    // o2: out = h1 @ o2^T + b2 + x  (in place in x_s)
#pragma unroll
    for (int s = 0; s < 4; s++)
        af2[s] = *(const bf16x8*)&a_s[(m16 + l15) * 136 + s * 32 + quad * 8];
#pragma unroll
    for (int t = 0; t < 4; t++) acc2[t] = (f32x4){0.f,0.f,0.f,0.f};
#pragma unroll
    for (int tt = 0; tt < 4; tt++) {
        int t = half * 4 + tt;
#pragma unroll
        for (int s = 0; s < 4; s++) {
            bf16x8 bf = *(const bf16x8*)(o2f + (size_t)((t * 4 + s) * 64 + lane) * 8);
            acc2[tt] = __builtin_amdgcn_mfma_f32_16x16x32_bf16(af2[s], bf, acc2[tt], 0, 0, 0);
        }
    }
#pragma unroll
    for (int tt = 0; tt < 4; tt++) {
        int t = half * 4 + tt;
        float bb = o2_b[t * 16 + l15];
#pragma unroll
        for (int r = 0; r < 4; r++) {
            int row = m16 + quad * 4 + r;
            int col = t * 16 + l15;
            x_s[col * 36 + row] = acc2[tt][r] + bb + x_s[col * 36 + row];
        }
    }
    __syncthreads();

    // store, coalesced fp32 [c][n]
    {
        int c = tid >> 1, nh = (tid & 1) * 16;
        float4* dst = (float4*)(out + ((size_t)(b * 128 + c)) * 16384 + n0 + nh);
        const float4* sv = (const float4*)&x_s[c * 36 + nh];
#pragma unroll
        for (int i = 0; i < 4; i++) dst[i] = sv[i];
    }
}

// ---------------------------------------------------------------------------
extern "C" void kernel_launch(void* const* d_in, const int* in_sizes, int n_in,
                              void* d_out, int out_size, void* d_ws, size_t ws_size,
                              hipStream_t stream) {
    (void)in_sizes; (void)n_in; (void)out_size; (void)ws_size;
    const float* x     = (const float*)d_in[0];
    const float* qkv_w = (const float*)d_in[1];
    const float* qkv_b = (const float*)d_in[2];
    const float* o1_w  = (const float*)d_in[3];
    const float* o1_b  = (const float*)d_in[4];
    const float* o2_w  = (const float*)d_in[5];
    const float* o2_b  = (const float*)d_in[6];
    const float* klw   = (const float*)d_in[7];
    const float* klb   = (const float*)d_in[8];
    const float* vlw   = (const float*)d_in[9];
    const float* vlb   = (const float*)d_in[10];
    float* outp = (float*)d_out;

    char* ws = (char*)d_ws;
    u16*   kvf  = (u16*)(ws);                    // 16384 bf16 (32 KB)
    u16*   wq   = (u16*)(ws + 32768);            // 49152 bf16 (96 KB)
    u16*   o1f  = (u16*)(ws + 131072);           // 16384 bf16 (32 KB)
    u16*   o2f  = (u16*)(ws + 163840);           // 16384 bf16 (32 KB)
    float* part = (float*)(ws + 196608);         // 2048*2048 f (16 MB)
    u16*   q_ws = (u16*)(ws + 196608 + 16777216); // 8*16384*128 bf16 (32 MB)

    prep_kernel<<<320, 256, 0, stream>>>(qkv_w, o1_w, o2_w, wq, o1f, o2f);
    k1<<<2048, 512, 0, stream>>>(x, wq, qkv_b, klw, klb, vlw, vlb, q_ws, part);
    k_red<<<64, 256, 0, stream>>>(part, kvf);
    k2<<<4096, 256, 0, stream>>>(x, q_ws, kvf, o1f, o2f, o1_b, o2_b, outp);
}

// Round 3
// 221.531 us; speedup vs baseline: 1.2091x; 1.1325x over previous
//
#include <hip/hip_runtime.h>
#include <hip/hip_bf16.h>

#define LN_EPS 1e-5f

typedef __bf16 bf16x8 __attribute__((ext_vector_type(8)));
typedef float  f32x4  __attribute__((ext_vector_type(4)));
typedef unsigned short u16;
typedef unsigned int u32;

__device__ __forceinline__ u16 f2bf(float f) {
    __bf16 b = (__bf16)f;
    return __builtin_bit_cast(u16, b);
}
__device__ __forceinline__ bf16x8 zero8() {
    bf16x8 v;
#pragma unroll
    for (int j = 0; j < 8; j++) v[j] = (__bf16)0.f;
    return v;
}
// tanh-form GELU in sigmoid shape: v * sigmoid(v*(1.59576912 + 0.07135482 v^2))
__device__ __forceinline__ float gelu_f(float v) {
    float t = v * fmaf(v * v, 0.0713548162726f, 1.5957691216057f);
    return v / (1.f + __expf(-t));
}

// ---------------------------------------------------------------------------
// prep: pack weights into bf16 MFMA B-fragment order (16x16x32).
// dst[((t*4+s)*64+l)*8+j] = bf16(src[(t*16+(l&15))*128 + s*32 + ((l>>4)&3)*8 + j])
// ---------------------------------------------------------------------------
__global__ __launch_bounds__(256) void prep_kernel(
    const float* __restrict__ qkv_w, const float* __restrict__ o1_w,
    const float* __restrict__ o2_w, u16* __restrict__ wq,
    u16* __restrict__ o1f, u16* __restrict__ o2f) {
    int i = blockIdx.x * 256 + threadIdx.x;
    if (i >= 81920) return;
    int j = i;
    const float* src;
    u16* dst;
    if (j < 49152) { src = qkv_w; dst = wq; }
    else if (j < 65536) { j -= 49152; src = o1_w; dst = o1f; }
    else { j -= 65536; src = o2_w; dst = o2f; }
    int jj = j & 7;
    int l  = (j >> 3) & 63;
    int s  = (j >> 9) & 3;
    int t  = j >> 11;
    int outc = t * 16 + (l & 15);
    int k    = s * 32 + ((l >> 4) & 3) * 8 + jj;
    dst[j] = f2bf(src[outc * 128 + k]);
}

// ---------------------------------------------------------------------------
// k1: qkv GEMM -> q direct to global; k,v -> LDS; per-row LN (head = wave,
// gamma/beta scalar); transposed kT/vT; k^T v via 2 MFMAs per head-wave.
// grid 2048 = B * (N/64); block 512 (8 waves)
// LDS overlay: x_a (17408B) -> kv_s (33792B) -> kT|vT (36864B), reg-staged.
// ---------------------------------------------------------------------------
__global__ __launch_bounds__(512, 6) void k1(
    const float* __restrict__ x, const u16* __restrict__ wq,
    const float* __restrict__ qkv_b,
    const float* __restrict__ klw, const float* __restrict__ klb,
    const float* __restrict__ vlw, const float* __restrict__ vlb,
    u16* __restrict__ q_ws, float* __restrict__ part) {
    __shared__ __align__(16) char Rbuf[36864];
    u16* x_a  = (u16*)Rbuf;           // [64 n][136] (cols 0..127 valid)
    u16* kv_s = (u16*)Rbuf;           // [64 n][264] cols h*32 + (k:0-15|v:16-31)
    u16* kT   = (u16*)Rbuf;           // [128 hd][72]
    u16* vT   = (u16*)Rbuf + 9216;    // [128 hd][72]

    const int tid  = threadIdx.x;
    const int lane = tid & 63;
    const int wv   = tid >> 6;
    const int stripe = wv >> 1;
    const int half   = wv & 1;
    const int bid  = blockIdx.x;
    const int b    = bid >> 8;
    const int n0   = (bid & 255) * 64;

    // phase 1: stage x -> x_a, packed b32 writes (conflict-free: banks = cw)
    {
        int cw  = tid & 63;     // channel pair
        int sub = tid >> 6;     // n octet
        const float* p0 = x + ((size_t)(b * 128 + 2 * cw)) * 16384 + n0 + sub * 8;
        const float* p1 = p0 + 16384;
        float4 a0 = ((const float4*)p0)[0], a1 = ((const float4*)p0)[1];
        float4 c0 = ((const float4*)p1)[0], c1 = ((const float4*)p1)[1];
        float av[8] = {a0.x, a0.y, a0.z, a0.w, a1.x, a1.y, a1.z, a1.w};
        float cv[8] = {c0.x, c0.y, c0.z, c0.w, c1.x, c1.y, c1.z, c1.w};
        u32* dst = (u32*)x_a;
#pragma unroll
        for (int j = 0; j < 8; j++)
            dst[(sub * 8 + j) * 68 + cw] = (u32)f2bf(av[j]) | ((u32)f2bf(cv[j]) << 16);
    }
    __syncthreads();

    const int m16  = stripe * 16;
    const int l15  = lane & 15;
    const int quad = lane >> 4;

    bf16x8 af[4];
#pragma unroll
    for (int s = 0; s < 4; s++)
        af[s] = *(const bf16x8*)&x_a[(m16 + l15) * 136 + s * 32 + quad * 8];
    __syncthreads();   // x_a dead -> kv_s may be written

    // phase 2: qkv GEMM; q straight to global; k,v (+bias) -> kv_s
    const int tb = half * 12;
#pragma unroll
    for (int hh = 0; hh < 4; hh++) {
        const int tq = tb + 3 * hh;
        f32x4 aq  = (f32x4){0.f, 0.f, 0.f, 0.f};
        f32x4 ak  = (f32x4){0.f, 0.f, 0.f, 0.f};
        f32x4 avv = (f32x4){0.f, 0.f, 0.f, 0.f};
#pragma unroll
        for (int s = 0; s < 4; s++) {
            bf16x8 bq = *(const bf16x8*)(wq + (size_t)(((tq + 0) * 4 + s) * 64 + lane) * 8);
            bf16x8 bk = *(const bf16x8*)(wq + (size_t)(((tq + 1) * 4 + s) * 64 + lane) * 8);
            bf16x8 bv = *(const bf16x8*)(wq + (size_t)(((tq + 2) * 4 + s) * 64 + lane) * 8);
            aq  = __builtin_amdgcn_mfma_f32_16x16x32_bf16(af[s], bq, aq, 0, 0, 0);
            ak  = __builtin_amdgcn_mfma_f32_16x16x32_bf16(af[s], bk, ak, 0, 0, 0);
            avv = __builtin_amdgcn_mfma_f32_16x16x32_bf16(af[s], bv, avv, 0, 0, 0);
        }
        const int h = half * 4 + hh;
        float biasq = qkv_b[(tq + 0) * 16 + l15];
        float biask = qkv_b[(tq + 1) * 16 + l15];
        float biasv = qkv_b[(tq + 2) * 16 + l15];
#pragma unroll
        for (int r = 0; r < 4; r++) {
            int row = m16 + quad * 4 + r;
            q_ws[((size_t)(b * 16384) + n0 + row) * 128 + h * 16 + l15] = f2bf(aq[r] + biasq);
            kv_s[row * 264 + h * 32 + l15]      = f2bf(ak[r] + biask);
            kv_s[row * 264 + h * 32 + 16 + l15] = f2bf(avv[r] + biasv);
        }
    }
    __syncthreads();

    // phase 3: per-row LN. thread = (head hL = wave, row = lane). gamma/beta scalar.
    const int hL = __builtin_amdgcn_readfirstlane(wv);
    const u16* rowp = &kv_s[lane * 264 + hL * 32];
    bf16x8 rk0 = *(const bf16x8*)(rowp);
    bf16x8 rk1 = *(const bf16x8*)(rowp + 8);
    bf16x8 rv0 = *(const bf16x8*)(rowp + 16);
    bf16x8 rv1 = *(const bf16x8*)(rowp + 24);
    __syncthreads();   // kv_s dead -> kT/vT overlay safe

    {
        float kf[16], vf[16];
#pragma unroll
        for (int j = 0; j < 8; j++) {
            kf[j] = (float)rk0[j]; kf[8 + j] = (float)rk1[j];
            vf[j] = (float)rv0[j]; vf[8 + j] = (float)rv1[j];
        }
        float ksum = 0.f, ksq = 0.f, vsum = 0.f, vsq = 0.f;
#pragma unroll
        for (int d = 0; d < 16; d++) {
            ksum += kf[d]; ksq = fmaf(kf[d], kf[d], ksq);
            vsum += vf[d]; vsq = fmaf(vf[d], vf[d], vsq);
        }
        float km = ksum * (1.f / 16.f);
        float kvar = (ksq - 16.f * km * km) * (1.f / 15.f);
        kvar = kvar < 0.f ? 0.f : kvar;
        float kinv = 1.f / (sqrtf(kvar) + LN_EPS);
        float vm = vsum * (1.f / 16.f);
        float vvar = (vsq - 16.f * vm * vm) * (1.f / 15.f);
        vvar = vvar < 0.f ? 0.f : vvar;
        float vinv = 1.f / (sqrtf(vvar) + LN_EPS);
        const float* kwp = klw + hL * 16; const float* kbp = klb + hL * 16;
        const float* vwp = vlw + hL * 16; const float* vbp = vlb + hL * 16;
#pragma unroll
        for (int d = 0; d < 16; d++) {
            kT[(hL * 16 + d) * 72 + lane] = f2bf(fmaf((kf[d] - km) * kinv, kwp[d], kbp[d]));
            vT[(hL * 16 + d) * 72 + lane] = f2bf(fmaf((vf[d] - vm) * vinv, vwp[d], vbp[d]));
        }
    }
    __syncthreads();

    // phase 4: kv partial for head hL over all 64 rows: 2 MFMAs, frags via b128
    {
        const u16* ka = &kT[(hL * 16 + l15) * 72 + quad * 8];
        const u16* vb = &vT[(hL * 16 + l15) * 72 + quad * 8];
        bf16x8 A0 = *(const bf16x8*)(ka);
        bf16x8 A1 = *(const bf16x8*)(ka + 32);
        bf16x8 B0 = *(const bf16x8*)(vb);
        bf16x8 B1 = *(const bf16x8*)(vb + 32);
        f32x4 kv = __builtin_amdgcn_mfma_f32_16x16x32_bf16(A0, B0, (f32x4){0.f,0.f,0.f,0.f}, 0, 0, 0);
        kv = __builtin_amdgcn_mfma_f32_16x16x32_bf16(A1, B1, kv, 0, 0, 0);
        ((f32x4*)part)[(size_t)(bid * 8 + hL) * 64 + lane] = kv;
    }
}

// ---------------------------------------------------------------------------
// k_red: kv = (1/N) * sum of partials (D-frag layout); emit bf16 B-fragment
// layout for k2: kvf[(b*8+h)*256 + (dk>>3)*128 + dv*8 + (dk&7)]
// ---------------------------------------------------------------------------
__global__ __launch_bounds__(256) void k_red(const float* __restrict__ part,
                                             u16* __restrict__ kvf) {
    int gid = blockIdx.x * 256 + threadIdx.x;   // 16384
    int b = gid >> 11, e = gid & 2047;
    int h = e >> 8, dk = (e >> 4) & 15, dv = e & 15;
    size_t base = (size_t)h * 256 + (size_t)(((dk >> 2) * 16 + dv) * 4 + (dk & 3));
    float s = 0.f;
    for (int t = 0; t < 256; t++)
        s += part[((size_t)(b * 256 + t)) * 2048 + base];
    kvf[(size_t)(b * 8 + h) * 256 + (dk >> 3) * 128 + dv * 8 + (dk & 7)] =
        f2bf(s * (1.f / 16384.f));
}

// ---------------------------------------------------------------------------
// k2: av = q@kv, ret = av+x, h1 = gelu(ret@o1^T+b1), out = h1@o2^T+b2+x
// grid 4096 = B * (N/32); block 256 (4 waves: 2 row-stripes x 2 tile-halves)
// ---------------------------------------------------------------------------
__global__ __launch_bounds__(256, 5) void k2(
    const float* __restrict__ x, const u16* __restrict__ q_ws,
    const u16* __restrict__ kvf, const u16* __restrict__ o1f,
    const u16* __restrict__ o2f, const float* __restrict__ o1_b,
    const float* __restrict__ o2_b, float* __restrict__ out) {
    __shared__ u16 a_s[32 * 136];      // q -> ret -> h1 (A-layout)
    __shared__ float x_s[128 * 36];    // x [c][n]; becomes out in place

    const int tid  = threadIdx.x;
    const int lane = tid & 63;
    const int wv   = tid >> 6;
    const int stripe = wv >> 1;
    const int half   = wv & 1;
    const int bid  = blockIdx.x;
    const int b    = bid >> 9;
    const int n0   = (bid & 511) * 32;

    // stage q and x
    {
        int row = tid >> 3, seg = tid & 7;
        const uint4* qs = (const uint4*)(q_ws + ((size_t)(b * 16384) + n0 + row) * 128 + seg * 16);
        uint4* qd = (uint4*)&a_s[row * 136 + seg * 16];
        qd[0] = qs[0];
        qd[1] = qs[1];

        int c = tid >> 1, nh = (tid & 1) * 16;
        const float4* xs = (const float4*)(x + ((size_t)(b * 128 + c)) * 16384 + n0 + nh);
        float4* xd = (float4*)&x_s[c * 36 + nh];
#pragma unroll
        for (int i = 0; i < 4; i++) xd[i] = xs[i];
    }
    __syncthreads();

    const int m16  = stripe * 16;
    const int l15  = lane & 15;
    const int quad = lane >> 4;
    const bool act = quad < 2;

    // av per head (4 heads per wave), ret = av + x
    float retv[4][4];
#pragma unroll
    for (int hh = 0; hh < 4; hh++) {
        int h = half * 4 + hh;
        bf16x8 afr = zero8(), bfr = zero8();
        if (act) {
            afr = *(const bf16x8*)&a_s[(m16 + l15) * 136 + h * 16 + quad * 8];
            bfr = *(const bf16x8*)(kvf + (size_t)(b * 8 + h) * 256 + quad * 128 + l15 * 8);
        }
        f32x4 acc = __builtin_amdgcn_mfma_f32_16x16x32_bf16(
            afr, bfr, (f32x4){0.f,0.f,0.f,0.f}, 0, 0, 0);
#pragma unroll
        for (int r = 0; r < 4; r++)
            retv[hh][r] = acc[r] + x_s[(h * 16 + l15) * 36 + m16 + quad * 4 + r];
    }
#pragma unroll
    for (int hh = 0; hh < 4; hh++)
#pragma unroll
        for (int r = 0; r < 4; r++)
            a_s[(m16 + quad * 4 + r) * 136 + (half * 4 + hh) * 16 + l15] = f2bf(retv[hh][r]);
    __syncthreads();

    // o1: 4 t-tiles per wave over full-128 rows
    bf16x8 af2[4];
#pragma unroll
    for (int s = 0; s < 4; s++)
        af2[s] = *(const bf16x8*)&a_s[(m16 + l15) * 136 + s * 32 + quad * 8];
    f32x4 acc2[4];
#pragma unroll
    for (int t = 0; t < 4; t++) acc2[t] = (f32x4){0.f,0.f,0.f,0.f};
#pragma unroll
    for (int tt = 0; tt < 4; tt++) {
        int t = half * 4 + tt;
#pragma unroll
        for (int s = 0; s < 4; s++) {
            bf16x8 bf = *(const bf16x8*)(o1f + (size_t)((t * 4 + s) * 64 + lane) * 8);
            acc2[tt] = __builtin_amdgcn_mfma_f32_16x16x32_bf16(af2[s], bf, acc2[tt], 0, 0, 0);
        }
    }
    float g[4][4];
#pragma unroll
    for (int tt = 0; tt < 4; tt++) {
        float bb = o1_b[(half * 4 + tt) * 16 + l15];
#pragma unroll
        for (int r = 0; r < 4; r++)
            g[tt][r] = gelu_f(acc2[tt][r] + bb);
    }
    __syncthreads();    // all ret-fragment reads done
#pragma unroll
    for (int tt = 0; tt < 4; tt++)
#pragma unroll
        for (int r = 0; r < 4; r++)
            a_s[(m16 + quad * 4 + r) * 136 + (half * 4 + tt) * 16 + l15] = f2bf(g[tt][r]);
    __syncthreads();

    // o2: out = h1 @ o2^T + b2 + x  (in place in x_s)
#pragma unroll
    for (int s = 0; s < 4; s++)
        af2[s] = *(const bf16x8*)&a_s[(m16 + l15) * 136 + s * 32 + quad * 8];
#pragma unroll
    for (int t = 0; t < 4; t++) acc2[t] = (f32x4){0.f,0.f,0.f,0.f};
#pragma unroll
    for (int tt = 0; tt < 4; tt++) {
        int t = half * 4 + tt;
#pragma unroll
        for (int s = 0; s < 4; s++) {
            bf16x8 bf = *(const bf16x8*)(o2f + (size_t)((t * 4 + s) * 64 + lane) * 8);
            acc2[tt] = __builtin_amdgcn_mfma_f32_16x16x32_bf16(af2[s], bf, acc2[tt], 0, 0, 0);
        }
    }
#pragma unroll
    for (int tt = 0; tt < 4; tt++) {
        int t = half * 4 + tt;
        float bb = o2_b[t * 16 + l15];
#pragma unroll
        for (int r = 0; r < 4; r++) {
            int row = m16 + quad * 4 + r;
            int col = t * 16 + l15;
            x_s[col * 36 + row] = acc2[tt][r] + bb + x_s[col * 36 + row];
        }
    }
    __syncthreads();

    // store, coalesced fp32 [c][n]
    {
        int c = tid >> 1, nh = (tid & 1) * 16;
        float4* dst = (float4*)(out + ((size_t)(b * 128 + c)) * 16384 + n0 + nh);
        const float4* sv = (const float4*)&x_s[c * 36 + nh];
#pragma unroll
        for (int i = 0; i < 4; i++) dst[i] = sv[i];
    }
}

// ---------------------------------------------------------------------------
extern "C" void kernel_launch(void* const* d_in, const int* in_sizes, int n_in,
                              void* d_out, int out_size, void* d_ws, size_t ws_size,
                              hipStream_t stream) {
    (void)in_sizes; (void)n_in; (void)out_size; (void)ws_size;
    const float* x     = (const float*)d_in[0];
    const float* qkv_w = (const float*)d_in[1];
    const float* qkv_b = (const float*)d_in[2];
    const float* o1_w  = (const float*)d_in[3];
    const float* o1_b  = (const float*)d_in[4];
    const float* o2_w  = (const float*)d_in[5];
    const float* o2_b  = (const float*)d_in[6];
    const float* klw   = (const float*)d_in[7];
    const float* klb   = (const float*)d_in[8];
    const float* vlw   = (const float*)d_in[9];
    const float* vlb   = (const float*)d_in[10];
    float* outp = (float*)d_out;

    char* ws = (char*)d_ws;
    u16*   kvf  = (u16*)(ws);                     // 16384 bf16 (32 KB)
    u16*   wq   = (u16*)(ws + 32768);             // 49152 bf16 (96 KB)
    u16*   o1f  = (u16*)(ws + 131072);            // 16384 bf16 (32 KB)
    u16*   o2f  = (u16*)(ws + 163840);            // 16384 bf16 (32 KB)
    float* part = (float*)(ws + 196608);          // 2048*2048 f (16 MB)
    u16*   q_ws = (u16*)(ws + 196608 + 16777216); // 8*16384*128 bf16 (32 MB)

    prep_kernel<<<320, 256, 0, stream>>>(qkv_w, o1_w, o2_w, wq, o1f, o2f);
    k1<<<2048, 512, 0, stream>>>(x, wq, qkv_b, klw, klb, vlw, vlb, q_ws, part);
    k_red<<<64, 256, 0, stream>>>(part, kvf);
    k2<<<4096, 256, 0, stream>>>(x, q_ws, kvf, o1f, o2f, o1_b, o2_b, outp);
}

// Round 4
// 207.043 us; speedup vs baseline: 1.2937x; 1.0700x over previous
//
#include <hip/hip_runtime.h>
#include <hip/hip_bf16.h>

#define LN_EPS 1e-5f

typedef __bf16 bf16x8 __attribute__((ext_vector_type(8)));
typedef float  f32x4  __attribute__((ext_vector_type(4)));
typedef unsigned short u16;
typedef unsigned int u32;

__device__ __forceinline__ u16 f2bf(float f) {
    __bf16 b = (__bf16)f;
    return __builtin_bit_cast(u16, b);
}
__device__ __forceinline__ bf16x8 zero8() {
    bf16x8 v;
#pragma unroll
    for (int j = 0; j < 8; j++) v[j] = (__bf16)0.f;
    return v;
}
// tanh-form GELU: v * sigmoid(v*(1.59576912 + 0.07135482 v^2))
__device__ __forceinline__ float gelu_f(float v) {
    float t = v * fmaf(v * v, 0.0713548162726f, 1.5957691216057f);
    return v / (1.f + __expf(-t));
}

// ---------------------------------------------------------------------------
// prep: pack weights into bf16 MFMA B-fragment order (16x16x32).
// dst[((t*4+s)*64+l)*8+j] = bf16(src[(t*16+(l&15))*128 + s*32 + ((l>>4)&3)*8 + j])
// ---------------------------------------------------------------------------
__global__ __launch_bounds__(256) void prep_kernel(
    const float* __restrict__ qkv_w, const float* __restrict__ o1_w,
    const float* __restrict__ o2_w, u16* __restrict__ wq,
    u16* __restrict__ o1f, u16* __restrict__ o2f) {
    int i = blockIdx.x * 256 + threadIdx.x;
    if (i >= 81920) return;
    int j = i;
    const float* src;
    u16* dst;
    if (j < 49152) { src = qkv_w; dst = wq; }
    else if (j < 65536) { j -= 49152; src = o1_w; dst = o1f; }
    else { j -= 65536; src = o2_w; dst = o2f; }
    int jj = j & 7;
    int l  = (j >> 3) & 63;
    int s  = (j >> 9) & 3;
    int t  = j >> 11;
    int outc = t * 16 + (l & 15);
    int k    = s * 32 + ((l >> 4) & 3) * 8 + jj;
    dst[j] = f2bf(src[outc * 128 + k]);
}

// ---------------------------------------------------------------------------
// k1: qkv GEMM; q -> LDS A-layout -> drained to q_ws in FRAGMENT order
// (so k2 reads A-frags directly from global, coalesced); per-row LN (head =
// wave, scalar gamma/beta); kT/vT transpose; k^T v via 2 MFMAs per head-wave.
// grid 2048 = B * (N/64); block 512 (8 waves: 4 row-stripes x 2 head-halves)
// LDS 51200B: [kv_s 33792 | q_s 17408]; x_a and kT/vT overlay kv_s/q_s.
// ---------------------------------------------------------------------------
__global__ __launch_bounds__(512, 6) void k1(
    const float* __restrict__ x, const u16* __restrict__ wq,
    const float* __restrict__ qkv_b,
    const float* __restrict__ klw, const float* __restrict__ klb,
    const float* __restrict__ vlw, const float* __restrict__ vlb,
    u16* __restrict__ q_ws, float* __restrict__ part) {
    __shared__ __align__(16) char Rbuf[51200];
    u16* x_a  = (u16*)Rbuf;            // [64 n][136] (phase 1-2)
    u16* kv_s = (u16*)Rbuf;            // [64 n][264] cols h*32 + (k:0-15|v:16-31)
    u16* q_s  = (u16*)(Rbuf + 33792);  // [64 n][136] A-layout q
    u16* kT   = (u16*)Rbuf;            // [128 hd][72] (phase 5-6)
    u16* vT   = (u16*)(Rbuf + 18432);  // [128 hd][72]

    const int tid  = threadIdx.x;
    const int lane = tid & 63;
    const int wv   = tid >> 6;
    const int stripe = wv >> 1;
    const int half   = wv & 1;
    const int bid  = blockIdx.x;
    const int b    = bid >> 8;
    const int n0   = (bid & 255) * 64;

    // phase 1: stage x -> x_a, packed b32 writes (conflict-free)
    {
        int cw  = tid & 63;     // channel pair
        int sub = tid >> 6;     // n octet
        const float* p0 = x + ((size_t)(b * 128 + 2 * cw)) * 16384 + n0 + sub * 8;
        const float* p1 = p0 + 16384;
        float4 a0 = ((const float4*)p0)[0], a1 = ((const float4*)p0)[1];
        float4 c0 = ((const float4*)p1)[0], c1 = ((const float4*)p1)[1];
        float av[8] = {a0.x, a0.y, a0.z, a0.w, a1.x, a1.y, a1.z, a1.w};
        float cv[8] = {c0.x, c0.y, c0.z, c0.w, c1.x, c1.y, c1.z, c1.w};
        u32* dst = (u32*)x_a;
#pragma unroll
        for (int j = 0; j < 8; j++)
            dst[(sub * 8 + j) * 68 + cw] = (u32)f2bf(av[j]) | ((u32)f2bf(cv[j]) << 16);
    }
    __syncthreads();

    const int m16  = stripe * 16;
    const int l15  = lane & 15;
    const int quad = lane >> 4;

    bf16x8 af[4];
#pragma unroll
    for (int s = 0; s < 4; s++)
        af[s] = *(const bf16x8*)&x_a[(m16 + l15) * 136 + s * 32 + quad * 8];
    __syncthreads();   // x_a dead -> kv_s/q_s may be written

    // phase 3: qkv GEMM; q -> q_s (A-layout); k,v (+bias) -> kv_s
    const int tb = half * 12;
#pragma unroll
    for (int hh = 0; hh < 4; hh++) {
        const int tq = tb + 3 * hh;
        f32x4 aq  = (f32x4){0.f, 0.f, 0.f, 0.f};
        f32x4 ak  = (f32x4){0.f, 0.f, 0.f, 0.f};
        f32x4 avv = (f32x4){0.f, 0.f, 0.f, 0.f};
#pragma unroll
        for (int s = 0; s < 4; s++) {
            bf16x8 bq = *(const bf16x8*)(wq + (size_t)(((tq + 0) * 4 + s) * 64 + lane) * 8);
            bf16x8 bk = *(const bf16x8*)(wq + (size_t)(((tq + 1) * 4 + s) * 64 + lane) * 8);
            bf16x8 bv = *(const bf16x8*)(wq + (size_t)(((tq + 2) * 4 + s) * 64 + lane) * 8);
            aq  = __builtin_amdgcn_mfma_f32_16x16x32_bf16(af[s], bq, aq, 0, 0, 0);
            ak  = __builtin_amdgcn_mfma_f32_16x16x32_bf16(af[s], bk, ak, 0, 0, 0);
            avv = __builtin_amdgcn_mfma_f32_16x16x32_bf16(af[s], bv, avv, 0, 0, 0);
        }
        const int h = half * 4 + hh;
        float biasq = qkv_b[(tq + 0) * 16 + l15];
        float biask = qkv_b[(tq + 1) * 16 + l15];
        float biasv = qkv_b[(tq + 2) * 16 + l15];
#pragma unroll
        for (int r = 0; r < 4; r++) {
            int row = m16 + quad * 4 + r;
            q_s[row * 136 + h * 16 + l15]       = f2bf(aq[r] + biasq);
            kv_s[row * 264 + h * 32 + l15]      = f2bf(ak[r] + biask);
            kv_s[row * 264 + h * 32 + 16 + l15] = f2bf(avv[r] + biasv);
        }
    }
    __syncthreads();

    // phase 4a: drain q_s -> q_ws in fragment order (coalesced b128 stores)
    {
#pragma unroll
        for (int p = 0; p < 2; p++) {
            int c = tid + p * 512;           // chunk id, 1024 total
            int lane_c = c & 63;
            int s  = (c >> 6) & 3;
            int tl = c >> 8;                 // local tile 0..3
            int row = tl * 16 + (lane_c & 15);
            const uint4* src = (const uint4*)&q_s[row * 136 + s * 32 + (lane_c >> 4) * 8];
            size_t gtile = (size_t)b * 1024 + (n0 >> 4) + tl;
            *(uint4*)(q_ws + gtile * 2048 + s * 512 + lane_c * 8) = *src;
        }
    }
    // phase 4b: per-row LN. thread = (head hL = wave, row = lane).
    const int hL = __builtin_amdgcn_readfirstlane(wv);
    const u16* rowp = &kv_s[lane * 264 + hL * 32];
    bf16x8 rk0 = *(const bf16x8*)(rowp);
    bf16x8 rk1 = *(const bf16x8*)(rowp + 8);
    bf16x8 rv0 = *(const bf16x8*)(rowp + 16);
    bf16x8 rv1 = *(const bf16x8*)(rowp + 24);
    __syncthreads();   // kv_s/q_s dead -> kT/vT overlay safe

    {
        float kf[16], vf[16];
#pragma unroll
        for (int j = 0; j < 8; j++) {
            kf[j] = (float)rk0[j]; kf[8 + j] = (float)rk1[j];
            vf[j] = (float)rv0[j]; vf[8 + j] = (float)rv1[j];
        }
        float ksum = 0.f, ksq = 0.f, vsum = 0.f, vsq = 0.f;
#pragma unroll
        for (int d = 0; d < 16; d++) {
            ksum += kf[d]; ksq = fmaf(kf[d], kf[d], ksq);
            vsum += vf[d]; vsq = fmaf(vf[d], vf[d], vsq);
        }
        float km = ksum * (1.f / 16.f);
        float kvar = (ksq - 16.f * km * km) * (1.f / 15.f);
        kvar = kvar < 0.f ? 0.f : kvar;
        float kinv = 1.f / (sqrtf(kvar) + LN_EPS);
        float vm = vsum * (1.f / 16.f);
        float vvar = (vsq - 16.f * vm * vm) * (1.f / 15.f);
        vvar = vvar < 0.f ? 0.f : vvar;
        float vinv = 1.f / (sqrtf(vvar) + LN_EPS);
        const float* kwp = klw + hL * 16; const float* kbp = klb + hL * 16;
        const float* vwp = vlw + hL * 16; const float* vbp = vlb + hL * 16;
#pragma unroll
        for (int d = 0; d < 16; d++) {
            kT[(hL * 16 + d) * 72 + lane] = f2bf(fmaf((kf[d] - km) * kinv, kwp[d], kbp[d]));
            vT[(hL * 16 + d) * 72 + lane] = f2bf(fmaf((vf[d] - vm) * vinv, vwp[d], vbp[d]));
        }
    }
    __syncthreads();

    // phase 6: kv partial for head hL over all 64 rows: 2 MFMAs
    {
        const u16* ka = &kT[(hL * 16 + l15) * 72 + quad * 8];
        const u16* vb = &vT[(hL * 16 + l15) * 72 + quad * 8];
        bf16x8 A0 = *(const bf16x8*)(ka);
        bf16x8 A1 = *(const bf16x8*)(ka + 32);
        bf16x8 B0 = *(const bf16x8*)(vb);
        bf16x8 B1 = *(const bf16x8*)(vb + 32);
        f32x4 kv = __builtin_amdgcn_mfma_f32_16x16x32_bf16(A0, B0, (f32x4){0.f,0.f,0.f,0.f}, 0, 0, 0);
        kv = __builtin_amdgcn_mfma_f32_16x16x32_bf16(A1, B1, kv, 0, 0, 0);
        ((f32x4*)part)[(size_t)(bid * 8 + hL) * 64 + lane] = kv;
    }
}

// ---------------------------------------------------------------------------
// k_red: kv = (1/N) * sum over 256 tiles; emit bf16 B-fragment layout.
// grid 256 = b(8) x eg(32); block 256 = tchunk(4) x el(64); LDS combine.
// ---------------------------------------------------------------------------
__global__ __launch_bounds__(256) void k_red(const float* __restrict__ part,
                                             u16* __restrict__ kvf) {
    __shared__ float red[256];
    int tid = threadIdx.x;
    int b  = blockIdx.x >> 5;
    int eg = blockIdx.x & 31;
    int el = tid & 63;
    int tchunk = tid >> 6;
    int e = eg * 64 + el;
    int h = e >> 8, dk = (e >> 4) & 15, dv = e & 15;
    size_t off = (size_t)h * 256 + (size_t)(((dk >> 2) * 16 + dv) * 4 + (dk & 3));
    float s = 0.f;
#pragma unroll 8
    for (int t = tchunk * 64; t < tchunk * 64 + 64; t++)
        s += part[((size_t)(b * 256 + t)) * 2048 + off];
    red[tid] = s;
    __syncthreads();
    if (tid < 64) {
        float total = red[tid] + red[tid + 64] + red[tid + 128] + red[tid + 192];
        int e2 = eg * 64 + tid;
        int h2 = e2 >> 8, dk2 = (e2 >> 4) & 15, dv2 = e2 & 15;
        kvf[(size_t)(b * 8 + h2) * 256 + (dk2 >> 3) * 128 + dv2 * 8 + (dk2 & 7)] =
            f2bf(total * (1.f / 16384.f));
    }
}

// ---------------------------------------------------------------------------
// k2: av = q@kv, ret = av+x, h1 = gelu(ret@o1^T+b1), out = h1@o2^T+b2+x
// q A-frags read DIRECTLY from global (fragment-order q_ws), hoisted before
// the staging barrier. grid 4096 = B*(N/32); block 256 (2 stripes x 2 halves)
// ---------------------------------------------------------------------------
__global__ __launch_bounds__(256, 5) void k2(
    const float* __restrict__ x, const u16* __restrict__ q_ws,
    const u16* __restrict__ kvf, const u16* __restrict__ o1f,
    const u16* __restrict__ o2f, const float* __restrict__ o1_b,
    const float* __restrict__ o2_b, float* __restrict__ out) {
    __shared__ u16 a_s[32 * 136];      // ret -> h1 (A-layout)
    __shared__ float x_s[128 * 36];    // x [c][n]; becomes out in place

    const int tid  = threadIdx.x;
    const int lane = tid & 63;
    const int wv   = tid >> 6;
    const int stripe = wv >> 1;
    const int half   = wv & 1;
    const int bid  = blockIdx.x;
    const int b    = bid >> 9;
    const int n0   = (bid & 511) * 32;

    const int m16  = stripe * 16;
    const int l15  = lane & 15;
    const int quad = lane >> 4;
    const bool act = quad < 2;

    // hoisted global frag loads (independent of LDS): q A-frags + kv B-frags
    bf16x8 qf[4], kvb[4];
    {
        size_t gtile = (size_t)b * 1024 + (n0 >> 4) + stripe;
#pragma unroll
        for (int hh = 0; hh < 4; hh++) {
            int h = half * 4 + hh;
            if (act) {
                int laneq = ((h & 1) * 2 + quad) * 16 + l15;
                qf[hh]  = *(const bf16x8*)(q_ws + gtile * 2048 + (h >> 1) * 512 + laneq * 8);
                kvb[hh] = *(const bf16x8*)(kvf + (size_t)(b * 8 + h) * 256 + quad * 128 + l15 * 8);
            } else {
                qf[hh] = zero8(); kvb[hh] = zero8();
            }
        }
    }

    // stage x
    {
        int c = tid >> 1, nh = (tid & 1) * 16;
        const float4* xs = (const float4*)(x + ((size_t)(b * 128 + c)) * 16384 + n0 + nh);
        float4* xd = (float4*)&x_s[c * 36 + nh];
#pragma unroll
        for (int i = 0; i < 4; i++) xd[i] = xs[i];
    }
    __syncthreads();

    // av per head (4 heads per wave), ret = av + x
#pragma unroll
    for (int hh = 0; hh < 4; hh++) {
        int h = half * 4 + hh;
        f32x4 acc = __builtin_amdgcn_mfma_f32_16x16x32_bf16(
            qf[hh], kvb[hh], (f32x4){0.f,0.f,0.f,0.f}, 0, 0, 0);
#pragma unroll
        for (int r = 0; r < 4; r++) {
            float rv = acc[r] + x_s[(h * 16 + l15) * 36 + m16 + quad * 4 + r];
            a_s[(m16 + quad * 4 + r) * 136 + h * 16 + l15] = f2bf(rv);
        }
    }
    __syncthreads();

    // o1: 4 t-tiles per wave over full-128 rows
    bf16x8 af2[4];
#pragma unroll
    for (int s = 0; s < 4; s++)
        af2[s] = *(const bf16x8*)&a_s[(m16 + l15) * 136 + s * 32 + quad * 8];
    f32x4 acc2[4];
#pragma unroll
    for (int t = 0; t < 4; t++) acc2[t] = (f32x4){0.f,0.f,0.f,0.f};
#pragma unroll
    for (int tt = 0; tt < 4; tt++) {
        int t = half * 4 + tt;
#pragma unroll
        for (int s = 0; s < 4; s++) {
            bf16x8 bf = *(const bf16x8*)(o1f + (size_t)((t * 4 + s) * 64 + lane) * 8);
            acc2[tt] = __builtin_amdgcn_mfma_f32_16x16x32_bf16(af2[s], bf, acc2[tt], 0, 0, 0);
        }
    }
    float g[4][4];
#pragma unroll
    for (int tt = 0; tt < 4; tt++) {
        float bb = o1_b[(half * 4 + tt) * 16 + l15];
#pragma unroll
        for (int r = 0; r < 4; r++)
            g[tt][r] = gelu_f(acc2[tt][r] + bb);
    }
    __syncthreads();    // all ret-fragment reads done
#pragma unroll
    for (int tt = 0; tt < 4; tt++)
#pragma unroll
        for (int r = 0; r < 4; r++)
            a_s[(m16 + quad * 4 + r) * 136 + (half * 4 + tt) * 16 + l15] = f2bf(g[tt][r]);
    __syncthreads();

    // o2: out = h1 @ o2^T + b2 + x  (in place in x_s)
#pragma unroll
    for (int s = 0; s < 4; s++)
        af2[s] = *(const bf16x8*)&a_s[(m16 + l15) * 136 + s * 32 + quad * 8];
#pragma unroll
    for (int t = 0; t < 4; t++) acc2[t] = (f32x4){0.f,0.f,0.f,0.f};
#pragma unroll
    for (int tt = 0; tt < 4; tt++) {
        int t = half * 4 + tt;
#pragma unroll
        for (int s = 0; s < 4; s++) {
            bf16x8 bf = *(const bf16x8*)(o2f + (size_t)((t * 4 + s) * 64 + lane) * 8);
            acc2[tt] = __builtin_amdgcn_mfma_f32_16x16x32_bf16(af2[s], bf, acc2[tt], 0, 0, 0);
        }
    }
#pragma unroll
    for (int tt = 0; tt < 4; tt++) {
        int t = half * 4 + tt;
        float bb = o2_b[t * 16 + l15];
#pragma unroll
        for (int r = 0; r < 4; r++) {
            int row = m16 + quad * 4 + r;
            int col = t * 16 + l15;
            x_s[col * 36 + row] = acc2[tt][r] + bb + x_s[col * 36 + row];
        }
    }
    __syncthreads();

    // store, coalesced fp32 [c][n]
    {
        int c = tid >> 1, nh = (tid & 1) * 16;
        float4* dst = (float4*)(out + ((size_t)(b * 128 + c)) * 16384 + n0 + nh);
        const float4* sv = (const float4*)&x_s[c * 36 + nh];
#pragma unroll
        for (int i = 0; i < 4; i++) dst[i] = sv[i];
    }
}

// ---------------------------------------------------------------------------
extern "C" void kernel_launch(void* const* d_in, const int* in_sizes, int n_in,
                              void* d_out, int out_size, void* d_ws, size_t ws_size,
                              hipStream_t stream) {
    (void)in_sizes; (void)n_in; (void)out_size; (void)ws_size;
    const float* x     = (const float*)d_in[0];
    const float* qkv_w = (const float*)d_in[1];
    const float* qkv_b = (const float*)d_in[2];
    const float* o1_w  = (const float*)d_in[3];
    const float* o1_b  = (const float*)d_in[4];
    const float* o2_w  = (const float*)d_in[5];
    const float* o2_b  = (const float*)d_in[6];
    const float* klw   = (const float*)d_in[7];
    const float* klb   = (const float*)d_in[8];
    const float* vlw   = (const float*)d_in[9];
    const float* vlb   = (const float*)d_in[10];
    float* outp = (float*)d_out;

    char* ws = (char*)d_ws;
    u16*   kvf  = (u16*)(ws);                     // 16384 bf16 (32 KB)
    u16*   wq   = (u16*)(ws + 32768);             // 49152 bf16 (96 KB)
    u16*   o1f  = (u16*)(ws + 131072);            // 16384 bf16 (32 KB)
    u16*   o2f  = (u16*)(ws + 163840);            // 16384 bf16 (32 KB)
    float* part = (float*)(ws + 196608);          // 2048*2048 f (16 MB)
    u16*   q_ws = (u16*)(ws + 196608 + 16777216); // 8*16384*128 bf16 (32 MB)

    prep_kernel<<<320, 256, 0, stream>>>(qkv_w, o1_w, o2_w, wq, o1f, o2f);
    k1<<<2048, 512, 0, stream>>>(x, wq, qkv_b, klw, klb, vlw, vlb, q_ws, part);
    k_red<<<256, 256, 0, stream>>>(part, kvf);
    k2<<<4096, 256, 0, stream>>>(x, q_ws, kvf, o1f, o2f, o1_b, o2_b, outp);
}